// Round 9
// baseline (695.802 us; speedup 1.0000x reference)
//
#include <hip/hip_runtime.h>
#include <hip/hip_bf16.h>

typedef __attribute__((ext_vector_type(8))) short short8;
typedef __attribute__((ext_vector_type(4))) float floatx4;
typedef __attribute__((ext_vector_type(2))) int i32x2;
typedef unsigned short u16;

#define T_SZ 609
#define K1V  4872   // valid K of flattened LSTM output (609*8)
#define K1P  4896   // padded to multiple of 32
#define RD   16     // LDS ring depth (slots)

static __device__ __forceinline__ u16 f2bf(float f) {
    union { float f; unsigned u; } a; a.f = f;
    unsigned r = a.u + 0x7FFF + ((a.u >> 16) & 1);   // round-to-nearest-even
    return (u16)(r >> 16);
}

// async global->LDS, 16B per lane; LDS dest = wave-uniform base + lane*16
static __device__ __forceinline__ void gload_lds16(const u16* g, u16* l) {
    __builtin_amdgcn_global_load_lds(
        (const __attribute__((address_space(1))) void*)g,
        (__attribute__((address_space(3))) void*)l, 16, 0, 0);
}

#define WG_LOAD(p)     __hip_atomic_load((p), __ATOMIC_ACQUIRE, __HIP_MEMORY_SCOPE_WORKGROUP)
#define WG_STORE(p, v) __hip_atomic_store((p), (v), __ATOMIC_RELEASE, __HIP_MEMORY_SCOPE_WORKGROUP)

// ===================== cross-lane primitives (all HW-verified this session) =====================
template<int CTRL>
static __device__ __forceinline__ float dppf(float v) {
    union { float f; int i; } a, b;
    a.f = v;
    b.i = __builtin_amdgcn_update_dpp(0, a.i, CTRL, 0xF, 0xF, true);
    return b.f;
}

// dual-output 16-row swap of a value with itself (verified round 6+)
static __device__ __forceinline__ void pl16(float v, float& ev, float& od) {
    union { float f; int i; } a; a.f = v;
    i32x2 r = __builtin_amdgcn_permlane16_swap(a.i, a.i, false, false);
    union { int i; float f; } x, y; x.i = r.x; y.i = r.y;
    ev = x.f; od = y.f;
}

// 8-wide xor-distributed dot, butterfly FOLDED INTO the FMA chain:
// acc += sum_{m=0..7} w[m] * (h from lane^m within each 8-lane group).
// Weights must be stored xor-ordered: w[m] = W[row, j^m]. Identical math to the
// old bfly2+pk_fma path (verified rounds 2-8) with ~40% fewer instructions:
// no f32x2 packing, no separate butterfly array, mov_dpp can fuse into v_fmac.
static __device__ __forceinline__ float dotx(const float* w, float h, float acc) {
    acc = __builtin_fmaf(w[0], h, acc);
    acc = __builtin_fmaf(w[1], dppf<0xB1>(h), acc);   // xor1 (quad_perm 1,0,3,2)
    acc = __builtin_fmaf(w[2], dppf<0x4E>(h), acc);   // xor2
    acc = __builtin_fmaf(w[3], dppf<0x1B>(h), acc);   // xor3
    float m7 = dppf<0x141>(h);                        // row_half_mirror = xor7
    acc = __builtin_fmaf(w[7], m7, acc);
    acc = __builtin_fmaf(w[6], dppf<0xB1>(m7), acc);  // xor6
    acc = __builtin_fmaf(w[5], dppf<0x4E>(m7), acc);  // xor5
    acc = __builtin_fmaf(w[4], dppf<0x1B>(m7), acc);  // xor4
    return acc;
}

// tanh(x) = 2*sigmoid(2x) - 1  (saturates correctly at +/-inf)
static __device__ __forceinline__ float tns(float a) {
    return __builtin_fmaf(2.f, __fdividef(1.f, 1.f + __expf(-2.f * a)), -1.f);
}

static __device__ __forceinline__ void cvt8(const float* __restrict__ p, u16* __restrict__ d) {
    float4 a = *(const float4*)p;
    float4 b = *(const float4*)(p + 4);
    u16 o[8] = { f2bf(a.x), f2bf(a.y), f2bf(a.z), f2bf(a.w),
                 f2bf(b.x), f2bf(b.y), f2bf(b.z), f2bf(b.w) };
    *(uint4*)d = *(const uint4*)o;
}
static __device__ __forceinline__ void zero8(u16* __restrict__ d) {
    *(uint4*)d = (uint4){0, 0, 0, 0};
}

// ============================ LSTM (3-wave pipeline v3) + fused weight cvt ============================
// Round-9 diet of the proven round-7 structure (s_sleep removed: measured neutral).
// Per-wave per-step stream shrunk ~40%:
//  - dots via dotx (xor-DPP folded into FMA chain) -- replaces bfly2 + f32x2 pk dots
//  - ring reads 1x ds_read_b32/step (DPP redistributes) -- replaces 2x ds_read_b128
//  - QUAD-UNROLLED t-loop with register double-buffer (hc/hn, poll-ahead p>=t0+8):
//    polls, flag stores, addressing, loop ctl amortized 4x; prefetch latency hidden.
// Deadlock bounds: L1 lead <= c2+12 < ring 16; poll-ahead feasible since producer
// throttle allows +8; all releases at quad ends (+ tail at 609). lfin unchanged.
__global__ __launch_bounds__(192) void lstm3_fused(
    const float* __restrict__ x,
    const float* __restrict__ Wih1, const float* __restrict__ Whh1,
    const float* __restrict__ bih1, const float* __restrict__ bhh1,
    const float* __restrict__ Wih2, const float* __restrict__ Whh2,
    const float* __restrict__ bih2, const float* __restrict__ bhh2,
    const float* __restrict__ Wih3, const float* __restrict__ Whh3,
    const float* __restrict__ bih3, const float* __restrict__ bhh3,
    u16* __restrict__ A1,
    const float* __restrict__ W1, u16* __restrict__ W1b,
    const float* __restrict__ W2, u16* __restrict__ W2b,
    const float* __restrict__ W3, u16* __restrict__ W3b)
{
    // ---------------- cvt role ----------------
    if (blockIdx.x >= 1024) {
        const int ct = (blockIdx.x - 1024) * 192 + threadIdx.x;
        const int cs = 256 * 192;
        for (int i = ct; i < 4096 * 612; i += cs) {          // W1: 4096 x 4896 (K pad)
            int r = i / 612, c = (i - r * 612) << 3;
            u16* d = W1b + (size_t)r * K1P + c;
            if (c < K1V) cvt8(W1 + (size_t)r * K1V + c, d); else zero8(d);
        }
        for (int i = ct; i < 524288; i += cs)                // W2: 1024 x 4096
            cvt8(W2 + (size_t)i * 8, W2b + (size_t)i * 8);
        for (int i = ct; i < 640 * 128; i += cs) {           // W3: 609 x 1024 -> 640 rows
            int r = i >> 7, c = (i & 127) << 3;
            u16* d = W3b + (size_t)r * 1024 + c;
            if (r < T_SZ) cvt8(W3 + (size_t)r * 1024 + c, d); else zero8(d);
        }
        return;
    }

    // ---------------- LSTM role ----------------
    __shared__ __align__(16) float xs[2 * T_SZ * 5];          // 24,360 B
    __shared__ __align__(16) float r1[RD * 16], r2[RD * 16];  // 1 KB each
    __shared__ int p1, p2, c2, c3;

    const int tid = threadIdx.x;
    const int b0  = blockIdx.x * 2;

    const float* xg = x + (size_t)b0 * (T_SZ * 5);
    for (int i = tid; i < 2 * T_SZ * 5; i += 192) xs[i] = xg[i];
    if (tid == 0) { p1 = 0; p2 = 0; c2 = 0; c3 = 0; }
    // zero the K padding columns of A1 (ws is poisoned each launch): 2 rows x 24 cols
    if (tid < 48) {
        int rr = tid / 24, cc = tid - rr * 24;
        A1[(size_t)(b0 + rr) * K1P + K1V + cc] = 0;
    }
    __syncthreads();

    const int lane = tid & 63, wid = tid >> 6;
    const int rh   = lane >> 5;          // row within block (0/1)
    const int gj   = lane & 31;
    const int grp  = gj >> 3;            // 0:i 1:g~ 2:f 3:o
    const int j    = gj & 7;             // hidden unit
    const int ptg  = (grp == 1) ? 2 : ((grp == 2) ? 1 : grp);   // grp -> PyTorch gate
    const int G    = ptg * 8 + j;        // row in the 4H weight matrices

    // branchless activation constants: sigmoid for i/f/o, tanh (=2*sigm(2x)-1) for g~
    const float am = (grp == 1) ? -2.f : -1.f;
    const float aa = (grp == 1) ?  2.f :  1.f;
    const float ab = (grp == 1) ? -1.f :  0.f;
    const bool  isf = (grp == 2);

    // layer finish: gate preact -> (c,h); h returned valid on ALL lanes. (verified r6-r8)
    auto lfin = [&](float a, float cin, float& cout) -> float {
        float e   = __expf(am * a);
        float v   = __builtin_fmaf(aa, __fdividef(1.f, 1.f + e), ab);
        float w1_ = dppf<0x128>(v);              // row_ror:8 = xor8 within 16-lane row
        float ig  = v * w1_;                     // low 16: i*g~
        float fv  = isf ? v : w1_;               // high 16: f
        float m   = (lane & 16) ? fv : ig;
        float igA, ffA; pl16(m, igA, ffA);
        float cn  = __builtin_fmaf(ffA, cin, igA);   // replicated on all lanes
        cout = cn;
        float th  = tns(cn);
        float ov  = isf ? w1_ : v;               // high 16: o
        float h   = ov * th;
        float he, ho; pl16(h, he, ho);           // ho = valid h bcast
        return ho;
    };

    const int rj = rh * 8 + j;           // ring offset within a slot

    if (wid == 0) {
        // ---------------- L1 wave (producer of r1/p1, throttled by c2) ----------------
        float wiv[8], whv[8];
#pragma unroll
        for (int m = 0; m < 8; ++m) {
            int k = j ^ m;
            wiv[m] = (k < 5) ? Wih1[G * 5 + k] : 0.f;
            whv[m] = Whh1[G * 8 + k];
        }
        const float bs = bih1[G] + bhh1[G];
        const int jx = (j < 5) ? j : 0;  // lanes j>=5 load valid addr; weights zeroed
        const float* xr = &xs[rh * (T_SZ * 5)];
        float xc4[4], xn4[4];
#pragma unroll
        for (int q = 0; q < 4; ++q) xc4[q] = xr[q * 5 + jx];
        float h1r = 0.f, c1s = 0.f;
#pragma unroll 1
        for (int t0 = 0; t0 < 608; t0 += 4) {
            while (WG_LOAD(&c2) < t0 - 8) {}
            const float* xp = xr + (t0 + 4) * 5 + jx;    // OOB at t0=604 stays in LDS; unused
            xn4[0] = xp[0]; xn4[1] = xp[5]; xn4[2] = xp[10]; xn4[3] = xp[15];
            const int sb = (t0 & 15);
#pragma unroll
            for (int q = 0; q < 4; ++q) {
                float a = dotx(wiv, xc4[q], bs);
                float b = dotx(whv, h1r, 0.f);
                float cn; float hv = lfin(a + b, c1s, cn); c1s = cn; h1r = hv;
                if (grp == 0) r1[(sb + q) * 16 + rj] = hv;
            }
            if (lane == 0) WG_STORE(&p1, t0 + 4);
            xc4[0] = xn4[0]; xc4[1] = xn4[1]; xc4[2] = xn4[2]; xc4[3] = xn4[3];
        }
        {   // tail t = 608 (slot 0; c2 >= 600 already ensured by t0=604's poll margin)
            float a = dotx(wiv, xc4[0], bs);
            float b = dotx(whv, h1r, 0.f);
            float cn; float hv = lfin(a + b, c1s, cn);
            if (grp == 0) r1[0 * 16 + rj] = hv;
            if (lane == 0) WG_STORE(&p1, 609);
        }
    } else if (wid == 1) {
        // ---------------- L2 wave (consumer of r1, producer of r2, throttled by c3) ----------------
        float win[8], whn[8];
#pragma unroll
        for (int m = 0; m < 8; ++m) {
            int k = j ^ m;
            win[m] = Wih2[G * 8 + k];
            whn[m] = Whh2[G * 8 + k];
        }
        const float bs = bih2[G] + bhh2[G];
        while (WG_LOAD(&p1) < 4) {}
        float hc[4], hn[4];
        hc[0] = r1[0 * 16 + rj]; hc[1] = r1[1 * 16 + rj];
        hc[2] = r1[2 * 16 + rj]; hc[3] = r1[3 * 16 + rj];
        float h2r = 0.f, c2s = 0.f;
#pragma unroll 1
        for (int t0 = 0; t0 < 608; t0 += 4) {
            int pt = (t0 + 8 <= 609) ? t0 + 8 : 609;
            while (WG_LOAD(&p1) < pt) {}
            while (WG_LOAD(&c3) < t0 - 8) {}
            const float* s = &r1[((t0 + 4) & 15) * 16 + rj];   // next-quad prefetch
            hn[0] = s[0]; hn[1] = s[16]; hn[2] = s[32]; hn[3] = s[48];
            const int sb = (t0 & 15);
#pragma unroll
            for (int q = 0; q < 4; ++q) {
                float a = dotx(win, hc[q], bs);
                float b = dotx(whn, h2r, 0.f);
                float cn; float hv = lfin(a + b, c2s, cn); c2s = cn; h2r = hv;
                if (grp == 0) r2[(sb + q) * 16 + rj] = hv;
            }
            if (lane == 0) { WG_STORE(&c2, t0 + 4); WG_STORE(&p2, t0 + 4); }
            hc[0] = hn[0]; hc[1] = hn[1]; hc[2] = hn[2]; hc[3] = hn[3];
        }
        {   // tail t = 608 (data = hc[0], slot 0 prefetched last quad)
            float a = dotx(win, hc[0], bs);
            float b = dotx(whn, h2r, 0.f);
            float cn; float hv = lfin(a + b, c2s, cn);
            if (grp == 0) r2[0 * 16 + rj] = hv;
            if (lane == 0) { WG_STORE(&c2, 609); WG_STORE(&p2, 609); }
        }
    } else {
        // ---------------- L3 wave (consumer of r2, writes A1, releases c3) ----------------
        float win[8], whn[8];
#pragma unroll
        for (int m = 0; m < 8; ++m) {
            int k = j ^ m;
            win[m] = Wih3[G * 8 + k];
            whn[m] = Whh3[G * 8 + k];
        }
        const float bs = bih3[G] + bhh3[G];
        u16* outp = A1 + (size_t)(b0 + rh) * K1P;
        while (WG_LOAD(&p2) < 4) {}
        float hc[4], hn[4];
        hc[0] = r2[0 * 16 + rj]; hc[1] = r2[1 * 16 + rj];
        hc[2] = r2[2 * 16 + rj]; hc[3] = r2[3 * 16 + rj];
        float h3r = 0.f, c3s = 0.f;
#pragma unroll 1
        for (int t0 = 0; t0 < 608; t0 += 4) {
            int pt = (t0 + 8 <= 609) ? t0 + 8 : 609;
            while (WG_LOAD(&p2) < pt) {}
            const float* s = &r2[((t0 + 4) & 15) * 16 + rj];
            hn[0] = s[0]; hn[1] = s[16]; hn[2] = s[32]; hn[3] = s[48];
#pragma unroll
            for (int q = 0; q < 4; ++q) {
                float a = dotx(win, hc[q], bs);
                float b = dotx(whn, h3r, 0.f);
                float cn; float hv = lfin(a + b, c3s, cn); c3s = cn; h3r = hv;
                if (grp == 0) outp[(t0 + q) * 8 + j] = f2bf(hv);
            }
            if (lane == 0) WG_STORE(&c3, t0 + 4);
            hc[0] = hn[0]; hc[1] = hn[1]; hc[2] = hn[2]; hc[3] = hn[3];
        }
        {   // tail t = 608
            float a = dotx(win, hc[0], bs);
            float b = dotx(whn, h3r, 0.f);
            float cn; float hv = lfin(a + b, c3s, cn);
            if (grp == 0) outp[608 * 8 + j] = f2bf(hv);
            if (lane == 0) WG_STORE(&c3, 609);
        }
    }
}

// ============================ bf16 NT GEMM + bias + (ReLU) ============================
// C[m][n] = act( sum_k A[m][k]*B[n][k] + bias[n] ). 16x16x32 bf16 MFMA, BK=32,
// m97-style async staging: global_load_lds dwordx4, unpadded LDS (row = 32 u16).
template<int BM, int BN, bool RELU, bool NGUARD, bool OUTF32>
__global__ __launch_bounds__(256) void gemm_bt(
    const u16* __restrict__ A, int lda,
    const u16* __restrict__ B, int ldb,
    const float* __restrict__ bias,
    void* __restrict__ Cv, int ldc, int N, int K)
{
    constexpr int WM = BM / 2, WN = BN / 2;
    constexpr int TM = WM / 16, TN = WN / 16;
    __shared__ u16 As[BM * 32];
    __shared__ u16 Bs[BN * 32];

    const int tid = threadIdx.x;
    const int bm  = blockIdx.y * BM;
    const int bn  = blockIdx.x * BN;
    const int l   = tid & 63, w = tid >> 6;
    const int wr  = w >> 1, wc = w & 1;
    const int lr  = l & 15, q = l >> 4;
    const int lrow = l >> 2;            // staging: lane -> row within 16-row group
    const int lcol = (l & 3) << 3;      // staging: lane -> 8-elem chunk

    floatx4 acc[TM][TN];
#pragma unroll
    for (int i = 0; i < TM; ++i)
#pragma unroll
        for (int j = 0; j < TN; ++j) acc[i][j] = (floatx4){0.f, 0.f, 0.f, 0.f};

    const u16* Ab = A + (size_t)bm * lda;
    const u16* Bb = B + (size_t)bn * ldb;

    for (int k0 = 0; k0 < K; k0 += 32) {
#pragma unroll
        for (int i = 0; i < BM / 64; ++i) {
            int r0 = w * (BM / 4) + i * 16;
            gload_lds16(Ab + (size_t)(r0 + lrow) * lda + k0 + lcol, &As[r0 * 32]);
        }
#pragma unroll
        for (int i = 0; i < BN / 64; ++i) {
            int r0 = w * (BN / 4) + i * 16;
            gload_lds16(Bb + (size_t)(r0 + lrow) * ldb + k0 + lcol, &Bs[r0 * 32]);
        }
        __syncthreads();

        short8 fa[TM], fb[TN];
#pragma unroll
        for (int i = 0; i < TM; ++i)
            fa[i] = *(const short8*)&As[(wr * WM + i * 16 + lr) * 32 + q * 8];
#pragma unroll
        for (int j = 0; j < TN; ++j)
            fb[j] = *(const short8*)&Bs[(wc * WN + j * 16 + lr) * 32 + q * 8];
#pragma unroll
        for (int i = 0; i < TM; ++i)
#pragma unroll
            for (int j = 0; j < TN; ++j)
                acc[i][j] = __builtin_amdgcn_mfma_f32_16x16x32_bf16(fa[i], fb[j], acc[i][j], 0, 0, 0);
        __syncthreads();
    }

    // epilogue: C/D layout col = lane&15, row = (lane>>4)*4 + reg  [m89/m91]
#pragma unroll
    for (int j = 0; j < TN; ++j) {
        int n = bn + wc * WN + j * 16 + lr;
        bool nok = (!NGUARD) || (n < N);
        float bv = nok ? bias[n] : 0.f;
#pragma unroll
        for (int i = 0; i < TM; ++i) {
            int m0r = bm + wr * WM + i * 16 + q * 4;
#pragma unroll
            for (int r = 0; r < 4; ++r) {
                float vv = acc[i][j][r] + bv;
                if (RELU) vv = fmaxf(vv, 0.f);
                if (nok) {
                    size_t idx = (size_t)(m0r + r) * ldc + n;
                    if (OUTF32) ((float*)Cv)[idx] = vv;
                    else        ((u16*)Cv)[idx] = f2bf(vv);
                }
            }
        }
    }
}

// ============================ launch ============================
extern "C" void kernel_launch(void* const* d_in, const int* in_sizes, int n_in,
                              void* d_out, int out_size, void* d_ws, size_t ws_size,
                              hipStream_t stream)
{
    const float* x    = (const float*)d_in[0];
    const float* Wih1 = (const float*)d_in[1];
    const float* Whh1 = (const float*)d_in[2];
    const float* bih1 = (const float*)d_in[3];
    const float* bhh1 = (const float*)d_in[4];
    const float* Wih2 = (const float*)d_in[5];
    const float* Whh2 = (const float*)d_in[6];
    const float* bih2 = (const float*)d_in[7];
    const float* bhh2 = (const float*)d_in[8];
    const float* Wih3 = (const float*)d_in[9];
    const float* Whh3 = (const float*)d_in[10];
    const float* bih3 = (const float*)d_in[11];
    const float* bhh3 = (const float*)d_in[12];
    const float* W1 = (const float*)d_in[13];
    const float* b1 = (const float*)d_in[14];
    const float* W2 = (const float*)d_in[15];
    const float* b2 = (const float*)d_in[16];
    const float* W3 = (const float*)d_in[17];
    const float* b3 = (const float*)d_in[18];

    // ws layout (bf16 elems): A1[2048][4896], A2[2048][4096], A3[2048][1024],
    // W1b[4096][4896] (K-padded), W2b[1024][4096], W3b[640][1024] (row-padded). ~91 MB.
    u16* A1  = (u16*)d_ws;
    u16* A2  = A1  + (size_t)2048 * K1P;
    u16* A3  = A2  + (size_t)2048 * 4096;
    u16* W1b = A3  + (size_t)2048 * 1024;
    u16* W2b = W1b + (size_t)4096 * K1P;
    u16* W3b = W2b + (size_t)1024 * 4096;

    // LSTM (blocks 0..1023) + fused weight conversions (blocks 1024..1279)
    lstm3_fused<<<1280, 192, 0, stream>>>(x, Wih1, Whh1, bih1, bhh1,
                                          Wih2, Whh2, bih2, bhh2,
                                          Wih3, Whh3, bih3, bhh3, A1,
                                          W1, W1b, W2, W2b, W3, W3b);

    // L1: [2048,4896] x W1b[4096,4896] -> relu -> A2 [2048,4096]  (bf16 out)
    gemm_bt<128, 128, true, false, false><<<dim3(32, 16), 256, 0, stream>>>(
        A1, K1P, W1b, K1P, b1, A2, 4096, 4096, K1P);

    // L2: [2048,4096] x W2b[1024,4096] -> relu -> A3 [2048,1024]  (bf16 out)
    gemm_bt<64, 128, true, false, false><<<dim3(8, 32), 256, 0, stream>>>(
        A2, 4096, W2b, 4096, b2, A3, 1024, 1024, 4096);

    // L3: [2048,1024] x W3b[640,1024] -> d_out [2048,609]  (fp32 out, store N-guard)
    gemm_bt<64, 128, false, true, true><<<dim3(5, 32), 256, 0, stream>>>(
        A3, 1024, W3b, 1024, b3, d_out, T_SZ, T_SZ, 1024);
}

// Round 10
// 641.700 us; speedup vs baseline: 1.0843x; 1.0843x over previous
//
#include <hip/hip_runtime.h>
#include <hip/hip_bf16.h>

typedef __attribute__((ext_vector_type(8))) short short8;
typedef __attribute__((ext_vector_type(4))) float floatx4;
typedef unsigned short u16;

#define T_SZ 609
#define K1V  4872   // valid K of flattened LSTM output (609*8)
#define K1P  4928   // padded to multiple of 64 (BK=64 GEMM1)
#define RD   4      // LDS ring depth (slots)

static __device__ __forceinline__ u16 f2bf(float f) {
    union { float f; unsigned u; } a; a.f = f;
    unsigned r = a.u + 0x7FFF + ((a.u >> 16) & 1);   // round-to-nearest-even
    return (u16)(r >> 16);
}

// async global->LDS, 16B per lane; LDS dest = wave-uniform base + lane*16
static __device__ __forceinline__ void gload_lds16(const u16* g, u16* l) {
    __builtin_amdgcn_global_load_lds(
        (const __attribute__((address_space(1))) void*)g,
        (__attribute__((address_space(3))) void*)l, 16, 0, 0);
}

#define WG_LOAD(p)     __hip_atomic_load((p), __ATOMIC_ACQUIRE, __HIP_MEMORY_SCOPE_WORKGROUP)
#define WG_STORE(p, v) __hip_atomic_store((p), (v), __ATOMIC_RELEASE, __HIP_MEMORY_SCOPE_WORKGROUP)

static __device__ __forceinline__ void cvt8(const float* __restrict__ p, u16* __restrict__ d) {
    float4 a = *(const float4*)p;
    float4 b = *(const float4*)(p + 4);
    u16 o[8] = { f2bf(a.x), f2bf(a.y), f2bf(a.z), f2bf(a.w),
                 f2bf(b.x), f2bf(b.y), f2bf(b.z), f2bf(b.w) };
    *(uint4*)d = *(const uint4*)o;
}
static __device__ __forceinline__ void zero8(u16* __restrict__ d) {
    *(uint4*)d = (uint4){0, 0, 0, 0};
}

// ============================ LSTM (round-0 3-wave pipeline, VERBATIM) + fused cvt ============================
// LESSON (rounds 7-9): every DPP/permlane rewrite of the cross-lane traffic was SLOWER
// than round 0's ds_bpermute(__shfl) + b128 ring reads (338 -> 367 -> 396 us, VALUBusy
// rising with cross-lane op count). Cross-lane DPP ops are expensive issue consumers on
// this chip. So: round-0 LSTM core byte-for-byte, plus the one verified win since —
// weight fp32->bf16 conversion fused in as role-split blocks (1024..1279), overlapping
// the latency-bound LSTM waves (round-7 mechanism, ~25-30 us of serial cvt removed).
// Block = 2 batch rows, 3 waves: wave w runs LSTM layer w for both rows over all t.
// Lane layout: lane = rowhalf*32 + gate (i:0-7,f:8-15,g:16-23,o:24-31).
// h handoff L1->L2->L3 via depth-RD LDS rings with acquire/release flag counters.
__global__ __launch_bounds__(192) void lstm3_fused(
    const float* __restrict__ x,
    const float* __restrict__ Wih1, const float* __restrict__ Whh1,
    const float* __restrict__ bih1, const float* __restrict__ bhh1,
    const float* __restrict__ Wih2, const float* __restrict__ Whh2,
    const float* __restrict__ bih2, const float* __restrict__ bhh2,
    const float* __restrict__ Wih3, const float* __restrict__ Whh3,
    const float* __restrict__ bih3, const float* __restrict__ bhh3,
    u16* __restrict__ A1,
    const float* __restrict__ W1, u16* __restrict__ W1b,
    const float* __restrict__ W2, u16* __restrict__ W2b,
    const float* __restrict__ W3, u16* __restrict__ W3b)
{
    // ---------------- cvt role (blocks 1024..1279) ----------------
    if (blockIdx.x >= 1024) {
        const int ct = (blockIdx.x - 1024) * 192 + threadIdx.x;
        const int cs = 256 * 192;
        for (int i = ct; i < 4096 * 616; i += cs) {          // W1: 4096 x 4928 (K pad)
            int r = i / 616, c = (i - r * 616) << 3;
            u16* d = W1b + (size_t)r * K1P + c;
            if (c < K1V) cvt8(W1 + (size_t)r * K1V + c, d); else zero8(d);
        }
        for (int i = ct; i < 524288; i += cs)                // W2: 1024 x 4096
            cvt8(W2 + (size_t)i * 8, W2b + (size_t)i * 8);
        for (int i = ct; i < 640 * 128; i += cs) {           // W3: 609 x 1024 -> 640 rows
            int r = i >> 7, c = (i & 127) << 3;
            u16* d = W3b + (size_t)r * 1024 + c;
            if (r < T_SZ) cvt8(W3 + (size_t)r * 1024 + c, d); else zero8(d);
        }
        return;
    }

    // ---------------- LSTM role (round-0 core) ----------------
    __shared__ __align__(16) float xs[2 * T_SZ * 5];          // 24,360 B
    __shared__ __align__(16) float r1[RD * 16], r2[RD * 16], r3[RD * 16];
    __shared__ int p1, p2, c2, c3;

    const int tid = threadIdx.x;
    const int b0  = blockIdx.x * 2;

    const float* xg = x + (size_t)b0 * (T_SZ * 5);
    for (int i = tid; i < 2 * T_SZ * 5; i += 192) xs[i] = xg[i];
    if (tid == 0) { p1 = 0; p2 = 0; c2 = 0; c3 = 0; }
    // zero the K padding columns of A1 (ws is poisoned each launch): 2 rows x 56 cols
    if (tid < 112) {
        int r = tid / 56, c = tid - r * 56;
        A1[(size_t)(b0 + r) * K1P + K1V + c] = 0;
    }
    __syncthreads();

    const int lane = tid & 63, wid = tid >> 6;
    const int gi   = lane & 31;        // gate index
    const int rh   = lane >> 5;        // row half (0/1)
    const int jj   = gi & 7;           // hidden unit this lane owns
    const int gt   = gi >> 3;
    const int base = lane & 32;

    // branchless activation: sigmoid for i/f/o, tanh (=2*sigm(2x)-1) for g
    const float am = (gt == 2) ? -2.f : -1.f;
    const float aa = (gt == 2) ?  2.f :  1.f;
    const float ab = (gt == 2) ? -1.f :  0.f;

    // gate preact in, h out (valid in all lanes for own unit jj)
    auto lstep = [&](float a, float& c) -> float {
        float e = __expf(am * a);
        float v = __builtin_fmaf(aa, __fdividef(1.f, 1.f + e), ab);
        float vi = __shfl(v, base + jj,      64);
        float vf = __shfl(v, base + 8 + jj,  64);
        float vg = __shfl(v, base + 16 + jj, 64);
        float vo = __shfl(v, base + 24 + jj, 64);
        c = __builtin_fmaf(vf, c, vi * vg);
        float ec = __expf(-2.f * __builtin_fabsf(c));
        float th = (1.f - ec) * __fdividef(1.f, 1.f + ec);
        return vo * __builtin_copysignf(th, c);
    };

    // dot of 8 recurrent/input terms from a 16B-aligned LDS slot
    auto dot8 = [&](const float* hp, const float* w, float& a, float& b) {
        float4 h0 = *(const float4*)hp;
        float4 h1 = *(const float4*)(hp + 4);
        a = __builtin_fmaf(w[0], h0.x, a); b = __builtin_fmaf(w[1], h0.y, b);
        a = __builtin_fmaf(w[2], h0.z, a); b = __builtin_fmaf(w[3], h0.w, b);
        a = __builtin_fmaf(w[4], h1.x, a); b = __builtin_fmaf(w[5], h1.y, b);
        a = __builtin_fmaf(w[6], h1.z, a); b = __builtin_fmaf(w[7], h1.w, b);
    };

    if (wid == 0) {
        // ---------------- L1 wave ----------------
        float wi[5], wh[8];
#pragma unroll
        for (int k = 0; k < 5; ++k) wi[k] = Wih1[gi * 5 + k];
#pragma unroll
        for (int k = 0; k < 8; ++k) wh[k] = Whh1[gi * 8 + k];
        const float bs = bih1[gi] + bhh1[gi];
        const float* xr = &xs[rh * (T_SZ * 5)];
        float cst = 0.f;
        for (int t = 0; t < T_SZ; ++t) {
            float a = bs, b = 0.f;
#pragma unroll
            for (int k = 0; k < 5; ++k) a = __builtin_fmaf(wi[k], xr[t * 5 + k], a);
            if (t > 0) dot8(&r1[((t - 1) & (RD - 1)) * 16 + rh * 8], wh, a, b);
            float h = lstep(a + b, cst);
            if (t >= RD) while (WG_LOAD(&c2) < t - (RD - 1)) {}
            if (gi < 8) r1[(t & (RD - 1)) * 16 + rh * 8 + jj] = h;
            if (lane == 0) WG_STORE(&p1, t + 1);
        }
    } else if (wid == 1) {
        // ---------------- L2 wave ----------------
        float wi[8], wh[8];
#pragma unroll
        for (int k = 0; k < 8; ++k) { wi[k] = Wih2[gi * 8 + k]; wh[k] = Whh2[gi * 8 + k]; }
        const float bs = bih2[gi] + bhh2[gi];
        float cst = 0.f;
        for (int t = 0; t < T_SZ; ++t) {
            while (WG_LOAD(&p1) < t + 1) {}
            float a = bs, b = 0.f;
            dot8(&r1[(t & (RD - 1)) * 16 + rh * 8], wi, a, b);
            if (lane == 0) WG_STORE(&c2, t + 1);     // release: reads above are drained
            if (t > 0) dot8(&r2[((t - 1) & (RD - 1)) * 16 + rh * 8], wh, a, b);
            float h = lstep(a + b, cst);
            if (t >= RD) while (WG_LOAD(&c3) < t - (RD - 1)) {}
            if (gi < 8) r2[(t & (RD - 1)) * 16 + rh * 8 + jj] = h;
            if (lane == 0) WG_STORE(&p2, t + 1);
        }
    } else {
        // ---------------- L3 wave ----------------
        float wi[8], wh[8];
#pragma unroll
        for (int k = 0; k < 8; ++k) { wi[k] = Wih3[gi * 8 + k]; wh[k] = Whh3[gi * 8 + k]; }
        const float bs = bih3[gi] + bhh3[gi];
        float cst = 0.f;
        u16* outp = A1 + (size_t)(b0 + rh) * K1P;
        for (int t = 0; t < T_SZ; ++t) {
            while (WG_LOAD(&p2) < t + 1) {}
            float a = bs, b = 0.f;
            dot8(&r2[(t & (RD - 1)) * 16 + rh * 8], wi, a, b);
            if (lane == 0) WG_STORE(&c3, t + 1);
            if (t > 0) dot8(&r3[((t - 1) & (RD - 1)) * 16 + rh * 8], wh, a, b);
            float h = lstep(a + b, cst);
            if (gi < 8) {
                r3[(t & (RD - 1)) * 16 + rh * 8 + jj] = h;   // private ring (no flags)
                outp[t * 8 + jj] = f2bf(h);
            }
        }
    }
}

// ============================ bf16 NT GEMM + bias + (ReLU) ============================
// C[m][n] = act( sum_k A[m][k]*B[n][k] + bias[n] ). 16x16x32 bf16 MFMA, BK=64
// (2 MFMA k-steps per barrier pair -> half the vmcnt(0)+barrier drains of BK=32;
// LDS <=32 KB keeps ~3 blocks/CU, unlike m132's BK=128/64KB regression).
// m97-style async staging: global_load_lds dwordx4, unpadded LDS (row = 64 u16).
template<int BM, int BN, bool RELU, bool NGUARD, bool OUTF32>
__global__ __launch_bounds__(256) void gemm_bt(
    const u16* __restrict__ A, int lda,
    const u16* __restrict__ B, int ldb,
    const float* __restrict__ bias,
    void* __restrict__ Cv, int ldc, int N, int K)
{
    constexpr int WM = BM / 2, WN = BN / 2;
    constexpr int TM = WM / 16, TN = WN / 16;
    __shared__ u16 As[BM * 64];
    __shared__ u16 Bs[BN * 64];

    const int tid = threadIdx.x;
    const int bm  = blockIdx.y * BM;
    const int bn  = blockIdx.x * BN;
    const int l   = tid & 63, w = tid >> 6;
    const int wr  = w >> 1, wc = w & 1;
    const int lr  = l & 15, q = l >> 4;
    const int lrow = l >> 3;            // staging: 8 lanes/row (64 u16 = 128 B rows)
    const int lcol = (l & 7) << 3;      // staging: lane -> 8-elem chunk

    floatx4 acc[TM][TN];
#pragma unroll
    for (int i = 0; i < TM; ++i)
#pragma unroll
        for (int j = 0; j < TN; ++j) acc[i][j] = (floatx4){0.f, 0.f, 0.f, 0.f};

    const u16* Ab = A + (size_t)bm * lda;
    const u16* Bb = B + (size_t)bn * ldb;

    for (int k0 = 0; k0 < K; k0 += 64) {
#pragma unroll
        for (int i = 0; i < BM / 32; ++i) {      // each wave: BM/4 rows in BM/32 passes of 8
            int r0 = w * (BM / 4) + i * 8;
            gload_lds16(Ab + (size_t)(r0 + lrow) * lda + k0 + lcol, &As[r0 * 64]);
        }
#pragma unroll
        for (int i = 0; i < BN / 32; ++i) {
            int r0 = w * (BN / 4) + i * 8;
            gload_lds16(Bb + (size_t)(r0 + lrow) * ldb + k0 + lcol, &Bs[r0 * 64]);
        }
        __syncthreads();

#pragma unroll
        for (int ks = 0; ks < 2; ++ks) {
            short8 fa[TM], fb[TN];
#pragma unroll
            for (int i = 0; i < TM; ++i)
                fa[i] = *(const short8*)&As[(wr * WM + i * 16 + lr) * 64 + ks * 32 + q * 8];
#pragma unroll
            for (int j = 0; j < TN; ++j)
                fb[j] = *(const short8*)&Bs[(wc * WN + j * 16 + lr) * 64 + ks * 32 + q * 8];
#pragma unroll
            for (int i = 0; i < TM; ++i)
#pragma unroll
                for (int j = 0; j < TN; ++j)
                    acc[i][j] = __builtin_amdgcn_mfma_f32_16x16x32_bf16(fa[i], fb[j], acc[i][j], 0, 0, 0);
        }
        __syncthreads();
    }

    // epilogue: C/D layout col = lane&15, row = (lane>>4)*4 + reg  [m89/m91]
#pragma unroll
    for (int j = 0; j < TN; ++j) {
        int n = bn + wc * WN + j * 16 + lr;
        bool nok = (!NGUARD) || (n < N);
        float bv = nok ? bias[n] : 0.f;
#pragma unroll
        for (int i = 0; i < TM; ++i) {
            int m0r = bm + wr * WM + i * 16 + q * 4;
#pragma unroll
            for (int r = 0; r < 4; ++r) {
                float vv = acc[i][j][r] + bv;
                if (RELU) vv = fmaxf(vv, 0.f);
                if (nok) {
                    size_t idx = (size_t)(m0r + r) * ldc + n;
                    if (OUTF32) ((float*)Cv)[idx] = vv;
                    else        ((u16*)Cv)[idx] = f2bf(vv);
                }
            }
        }
    }
}

// ============================ launch ============================
extern "C" void kernel_launch(void* const* d_in, const int* in_sizes, int n_in,
                              void* d_out, int out_size, void* d_ws, size_t ws_size,
                              hipStream_t stream)
{
    const float* x    = (const float*)d_in[0];
    const float* Wih1 = (const float*)d_in[1];
    const float* Whh1 = (const float*)d_in[2];
    const float* bih1 = (const float*)d_in[3];
    const float* bhh1 = (const float*)d_in[4];
    const float* Wih2 = (const float*)d_in[5];
    const float* Whh2 = (const float*)d_in[6];
    const float* bih2 = (const float*)d_in[7];
    const float* bhh2 = (const float*)d_in[8];
    const float* Wih3 = (const float*)d_in[9];
    const float* Whh3 = (const float*)d_in[10];
    const float* bih3 = (const float*)d_in[11];
    const float* bhh3 = (const float*)d_in[12];
    const float* W1 = (const float*)d_in[13];
    const float* b1 = (const float*)d_in[14];
    const float* W2 = (const float*)d_in[15];
    const float* b2 = (const float*)d_in[16];
    const float* W3 = (const float*)d_in[17];
    const float* b3 = (const float*)d_in[18];

    // ws layout (bf16 elems): A1[2048][4928], A2[2048][4096], A3[2048][1024],
    // W1b[4096][4928] (K-padded), W2b[1024][4096], W3b[640][1024] (row-padded). ~91 MB.
    u16* A1  = (u16*)d_ws;
    u16* A2  = A1  + (size_t)2048 * K1P;
    u16* A3  = A2  + (size_t)2048 * 4096;
    u16* W1b = A3  + (size_t)2048 * 1024;
    u16* W2b = W1b + (size_t)4096 * K1P;
    u16* W3b = W2b + (size_t)1024 * 4096;

    // LSTM (blocks 0..1023, round-0 core) + fused weight conversions (blocks 1024..1279)
    lstm3_fused<<<1280, 192, 0, stream>>>(x, Wih1, Whh1, bih1, bhh1,
                                          Wih2, Whh2, bih2, bhh2,
                                          Wih3, Whh3, bih3, bhh3, A1,
                                          W1, W1b, W2, W2b, W3, W3b);

    // L1: [2048,4928] x W1b[4096,4928] -> relu -> A2 [2048,4096]  (bf16 out)
    gemm_bt<128, 128, true, false, false><<<dim3(32, 16), 256, 0, stream>>>(
        A1, K1P, W1b, K1P, b1, A2, 4096, 4096, K1P);

    // L2: [2048,4096] x W2b[1024,4096] -> relu -> A3 [2048,1024]  (bf16 out)
    gemm_bt<64, 128, true, false, false><<<dim3(8, 32), 256, 0, stream>>>(
        A2, 4096, W2b, 4096, b2, A3, 1024, 1024, 4096);

    // L3: [2048,1024] x W3b[640,1024] -> d_out [2048,609]  (fp32 out, store N-guard)
    gemm_bt<64, 64, false, true, true><<<dim3(10, 32), 256, 0, stream>>>(
        A3, 1024, W3b, 1024, b3, d_out, T_SZ, T_SZ, 1024);
}

// Round 12
// 597.698 us; speedup vs baseline: 1.1641x; 1.0736x over previous
//
#include <hip/hip_runtime.h>
#include <hip/hip_bf16.h>

typedef __attribute__((ext_vector_type(8))) short short8;
typedef __attribute__((ext_vector_type(4))) float floatx4;
typedef unsigned short u16;

#define T_SZ 609
#define K1V  4872   // valid K of flattened LSTM output (609*8)
#define K1P  4928   // padded to multiple of 64 (BK=64 GEMM1)
#define RD   8      // LDS ring depth (slots) — 2-step batched handshake needs 8

static __device__ __forceinline__ u16 f2bf(float f) {
    union { float f; unsigned u; } a; a.f = f;
    unsigned r = a.u + 0x7FFF + ((a.u >> 16) & 1);   // round-to-nearest-even
    return (u16)(r >> 16);
}

// async global->LDS, 16B per lane; LDS dest = wave-uniform base + lane*16
static __device__ __forceinline__ void gload_lds16(const u16* g, u16* l) {
    __builtin_amdgcn_global_load_lds(
        (const __attribute__((address_space(1))) void*)g,
        (__attribute__((address_space(3))) void*)l, 16, 0, 0);
}

#define WG_LOAD(p)     __hip_atomic_load((p), __ATOMIC_ACQUIRE, __HIP_MEMORY_SCOPE_WORKGROUP)
#define WG_STORE(p, v) __hip_atomic_store((p), (v), __ATOMIC_RELEASE, __HIP_MEMORY_SCOPE_WORKGROUP)

static __device__ __forceinline__ void cvt8(const float* __restrict__ p, u16* __restrict__ d) {
    float4 a = *(const float4*)p;
    float4 b = *(const float4*)(p + 4);
    u16 o[8] = { f2bf(a.x), f2bf(a.y), f2bf(a.z), f2bf(a.w),
                 f2bf(b.x), f2bf(b.y), f2bf(b.z), f2bf(b.w) };
    *(uint4*)d = *(const uint4*)o;
}
static __device__ __forceinline__ void zero8(u16* __restrict__ d) {
    *(uint4*)d = (uint4){0, 0, 0, 0};
}

// ============================ LSTM (r0 3-wave pipeline, 2-step batched handshake) + fused cvt ============================
// Round-10 banked the round-0 core (338 us) + fused cvt. Round-11 single change:
// each wave processes TWO timesteps per poll/release pair — halves the per-step
// handshake machinery (LDS flag polls ~130cy granularity, release stores, visibility
// waits) that accounts for the gap between the ~650cy serial chain and the measured
// 1330 cy/step. Consumer input-dots for both steps are hoisted before the release.
// RD=8: producer writes slots t0&7,(t0+1)&7 (prev occupants t0-8,t0-7) after polling
// consumer >= t0-6 (stronger than required t0-7) -> no clobber. Progress chain is
// acyclic (each wave waits only on strictly-earlier neighbor progress) -> no deadlock.
// Math/order identical to round 0 (same lstep, same dot8).
// Blocks 1024..1279: fp32->bf16 weight cvt (round-7 mechanism, verified).
// (Round-11 run died on container acquisition — same infra signature as round 3,
// which passed on identical resubmission. Resubmitted unchanged.)
__global__ __launch_bounds__(192) void lstm3_fused(
    const float* __restrict__ x,
    const float* __restrict__ Wih1, const float* __restrict__ Whh1,
    const float* __restrict__ bih1, const float* __restrict__ bhh1,
    const float* __restrict__ Wih2, const float* __restrict__ Whh2,
    const float* __restrict__ bih2, const float* __restrict__ bhh2,
    const float* __restrict__ Wih3, const float* __restrict__ Whh3,
    const float* __restrict__ bih3, const float* __restrict__ bhh3,
    u16* __restrict__ A1,
    const float* __restrict__ W1, u16* __restrict__ W1b,
    const float* __restrict__ W2, u16* __restrict__ W2b,
    const float* __restrict__ W3, u16* __restrict__ W3b)
{
    // ---------------- cvt role (blocks 1024..1279) ----------------
    if (blockIdx.x >= 1024) {
        const int ct = (blockIdx.x - 1024) * 192 + threadIdx.x;
        const int cs = 256 * 192;
        for (int i = ct; i < 4096 * 616; i += cs) {          // W1: 4096 x 4928 (K pad)
            int r = i / 616, c = (i - r * 616) << 3;
            u16* d = W1b + (size_t)r * K1P + c;
            if (c < K1V) cvt8(W1 + (size_t)r * K1V + c, d); else zero8(d);
        }
        for (int i = ct; i < 524288; i += cs)                // W2: 1024 x 4096
            cvt8(W2 + (size_t)i * 8, W2b + (size_t)i * 8);
        for (int i = ct; i < 640 * 128; i += cs) {           // W3: 609 x 1024 -> 640 rows
            int r = i >> 7, c = (i & 127) << 3;
            u16* d = W3b + (size_t)r * 1024 + c;
            if (r < T_SZ) cvt8(W3 + (size_t)r * 1024 + c, d); else zero8(d);
        }
        return;
    }

    // ---------------- LSTM role ----------------
    __shared__ __align__(16) float xs[2 * T_SZ * 5];          // 24,360 B
    __shared__ __align__(16) float r1[RD * 16], r2[RD * 16], r3[RD * 16];
    __shared__ int p1, p2, c2, c3;

    const int tid = threadIdx.x;
    const int b0  = blockIdx.x * 2;

    const float* xg = x + (size_t)b0 * (T_SZ * 5);
    for (int i = tid; i < 2 * T_SZ * 5; i += 192) xs[i] = xg[i];
    if (tid == 0) { p1 = 0; p2 = 0; c2 = 0; c3 = 0; }
    // zero the K padding columns of A1 (ws is poisoned each launch): 2 rows x 56 cols
    if (tid < 112) {
        int r = tid / 56, c = tid - r * 56;
        A1[(size_t)(b0 + r) * K1P + K1V + c] = 0;
    }
    __syncthreads();

    const int lane = tid & 63, wid = tid >> 6;
    const int gi   = lane & 31;        // gate index
    const int rh   = lane >> 5;        // row half (0/1)
    const int jj   = gi & 7;           // hidden unit this lane owns
    const int gt   = gi >> 3;
    const int base = lane & 32;

    // branchless activation: sigmoid for i/f/o, tanh (=2*sigm(2x)-1) for g
    const float am = (gt == 2) ? -2.f : -1.f;
    const float aa = (gt == 2) ?  2.f :  1.f;
    const float ab = (gt == 2) ? -1.f :  0.f;

    // gate preact in, h out (valid in all lanes for own unit jj)
    auto lstep = [&](float a, float& c) -> float {
        float e = __expf(am * a);
        float v = __builtin_fmaf(aa, __fdividef(1.f, 1.f + e), ab);
        float vi = __shfl(v, base + jj,      64);
        float vf = __shfl(v, base + 8 + jj,  64);
        float vg = __shfl(v, base + 16 + jj, 64);
        float vo = __shfl(v, base + 24 + jj, 64);
        c = __builtin_fmaf(vf, c, vi * vg);
        float ec = __expf(-2.f * __builtin_fabsf(c));
        float th = (1.f - ec) * __fdividef(1.f, 1.f + ec);
        return vo * __builtin_copysignf(th, c);
    };

    // dot of 8 recurrent/input terms from a 16B-aligned LDS slot
    auto dot8 = [&](const float* hp, const float* w, float& a, float& b) {
        float4 h0 = *(const float4*)hp;
        float4 h1 = *(const float4*)(hp + 4);
        a = __builtin_fmaf(w[0], h0.x, a); b = __builtin_fmaf(w[1], h0.y, b);
        a = __builtin_fmaf(w[2], h0.z, a); b = __builtin_fmaf(w[3], h0.w, b);
        a = __builtin_fmaf(w[4], h1.x, a); b = __builtin_fmaf(w[5], h1.y, b);
        a = __builtin_fmaf(w[6], h1.z, a); b = __builtin_fmaf(w[7], h1.w, b);
    };

    if (wid == 0) {
        // ---------------- L1 wave (2 steps per throttle check / release) ----------------
        float wi[5], wh[8];
#pragma unroll
        for (int k = 0; k < 5; ++k) wi[k] = Wih1[gi * 5 + k];
#pragma unroll
        for (int k = 0; k < 8; ++k) wh[k] = Whh1[gi * 8 + k];
        const float bs = bih1[gi] + bhh1[gi];
        const float* xr = &xs[rh * (T_SZ * 5)];
        float cst = 0.f;
        for (int t0 = 0; t0 < T_SZ - 1; t0 += 2) {
            while (WG_LOAD(&c2) < t0 - 6) {}
            // step t0
            float a = bs, b = 0.f;
#pragma unroll
            for (int k = 0; k < 5; ++k) a = __builtin_fmaf(wi[k], xr[t0 * 5 + k], a);
            if (t0 > 0) dot8(&r1[((t0 - 1) & 7) * 16 + rh * 8], wh, a, b);
            float h = lstep(a + b, cst);
            if (gi < 8) r1[(t0 & 7) * 16 + rh * 8 + jj] = h;
            // step t0+1
            float a2 = bs, b2 = 0.f;
#pragma unroll
            for (int k = 0; k < 5; ++k) a2 = __builtin_fmaf(wi[k], xr[(t0 + 1) * 5 + k], a2);
            dot8(&r1[(t0 & 7) * 16 + rh * 8], wh, a2, b2);
            float h2 = lstep(a2 + b2, cst);
            if (gi < 8) r1[((t0 + 1) & 7) * 16 + rh * 8 + jj] = h2;
            if (lane == 0) WG_STORE(&p1, t0 + 2);
        }
        {   // tail t = 608
            const int t = T_SZ - 1;
            while (WG_LOAD(&c2) < t - 6) {}
            float a = bs, b = 0.f;
#pragma unroll
            for (int k = 0; k < 5; ++k) a = __builtin_fmaf(wi[k], xr[t * 5 + k], a);
            dot8(&r1[((t - 1) & 7) * 16 + rh * 8], wh, a, b);
            float h = lstep(a + b, cst);
            if (gi < 8) r1[(t & 7) * 16 + rh * 8 + jj] = h;
            if (lane == 0) WG_STORE(&p1, T_SZ);
        }
    } else if (wid == 1) {
        // ---------------- L2 wave ----------------
        float wi[8], wh[8];
#pragma unroll
        for (int k = 0; k < 8; ++k) { wi[k] = Wih2[gi * 8 + k]; wh[k] = Whh2[gi * 8 + k]; }
        const float bs = bih2[gi] + bhh2[gi];
        float cst = 0.f;
        for (int t0 = 0; t0 < T_SZ - 1; t0 += 2) {
            while (WG_LOAD(&p1) < t0 + 2) {}
            while (WG_LOAD(&c3) < t0 - 6) {}
            // hoist both input dots, then release the r1 slots
            float a = bs, b = 0.f;
            dot8(&r1[(t0 & 7) * 16 + rh * 8], wi, a, b);
            float a2 = bs, b2 = 0.f;
            dot8(&r1[((t0 + 1) & 7) * 16 + rh * 8], wi, a2, b2);
            if (lane == 0) WG_STORE(&c2, t0 + 2);    // release: reads above drained
            // step t0
            if (t0 > 0) dot8(&r2[((t0 - 1) & 7) * 16 + rh * 8], wh, a, b);
            float h = lstep(a + b, cst);
            if (gi < 8) r2[(t0 & 7) * 16 + rh * 8 + jj] = h;
            // step t0+1
            dot8(&r2[(t0 & 7) * 16 + rh * 8], wh, a2, b2);
            float h2 = lstep(a2 + b2, cst);
            if (gi < 8) r2[((t0 + 1) & 7) * 16 + rh * 8 + jj] = h2;
            if (lane == 0) WG_STORE(&p2, t0 + 2);
        }
        {   // tail t = 608
            const int t = T_SZ - 1;
            while (WG_LOAD(&p1) < T_SZ) {}
            while (WG_LOAD(&c3) < t - 6) {}
            float a = bs, b = 0.f;
            dot8(&r1[(t & 7) * 16 + rh * 8], wi, a, b);
            if (lane == 0) WG_STORE(&c2, T_SZ);
            dot8(&r2[((t - 1) & 7) * 16 + rh * 8], wh, a, b);
            float h = lstep(a + b, cst);
            if (gi < 8) r2[(t & 7) * 16 + rh * 8 + jj] = h;
            if (lane == 0) WG_STORE(&p2, T_SZ);
        }
    } else {
        // ---------------- L3 wave ----------------
        float wi[8], wh[8];
#pragma unroll
        for (int k = 0; k < 8; ++k) { wi[k] = Wih3[gi * 8 + k]; wh[k] = Whh3[gi * 8 + k]; }
        const float bs = bih3[gi] + bhh3[gi];
        float cst = 0.f;
        u16* outp = A1 + (size_t)(b0 + rh) * K1P;
        for (int t0 = 0; t0 < T_SZ - 1; t0 += 2) {
            while (WG_LOAD(&p2) < t0 + 2) {}
            float a = bs, b = 0.f;
            dot8(&r2[(t0 & 7) * 16 + rh * 8], wi, a, b);
            float a2 = bs, b2 = 0.f;
            dot8(&r2[((t0 + 1) & 7) * 16 + rh * 8], wi, a2, b2);
            if (lane == 0) WG_STORE(&c3, t0 + 2);
            // step t0
            if (t0 > 0) dot8(&r3[((t0 - 1) & 7) * 16 + rh * 8], wh, a, b);
            float h = lstep(a + b, cst);
            if (gi < 8) {
                r3[(t0 & 7) * 16 + rh * 8 + jj] = h;     // private ring (no flags)
                outp[t0 * 8 + jj] = f2bf(h);
            }
            // step t0+1
            dot8(&r3[(t0 & 7) * 16 + rh * 8], wh, a2, b2);
            float h2 = lstep(a2 + b2, cst);
            if (gi < 8) {
                r3[((t0 + 1) & 7) * 16 + rh * 8 + jj] = h2;
                outp[(t0 + 1) * 8 + jj] = f2bf(h2);
            }
        }
        {   // tail t = 608
            const int t = T_SZ - 1;
            while (WG_LOAD(&p2) < T_SZ) {}
            float a = bs, b = 0.f;
            dot8(&r2[(t & 7) * 16 + rh * 8], wi, a, b);
            if (lane == 0) WG_STORE(&c3, T_SZ);
            dot8(&r3[((t - 1) & 7) * 16 + rh * 8], wh, a, b);
            float h = lstep(a + b, cst);
            if (gi < 8) outp[t * 8 + jj] = f2bf(h);
        }
    }
}

// ============================ bf16 NT GEMM + bias + (ReLU) ============================
// C[m][n] = act( sum_k A[m][k]*B[n][k] + bias[n] ). 16x16x32 bf16 MFMA, BK=64
// (2 MFMA k-steps per barrier pair). m97-style async staging: global_load_lds
// dwordx4, unpadded LDS (row = 64 u16).
template<int BM, int BN, bool RELU, bool NGUARD, bool OUTF32>
__global__ __launch_bounds__(256) void gemm_bt(
    const u16* __restrict__ A, int lda,
    const u16* __restrict__ B, int ldb,
    const float* __restrict__ bias,
    void* __restrict__ Cv, int ldc, int N, int K)
{
    constexpr int WM = BM / 2, WN = BN / 2;
    constexpr int TM = WM / 16, TN = WN / 16;
    __shared__ u16 As[BM * 64];
    __shared__ u16 Bs[BN * 64];

    const int tid = threadIdx.x;
    const int bm  = blockIdx.y * BM;
    const int bn  = blockIdx.x * BN;
    const int l   = tid & 63, w = tid >> 6;
    const int wr  = w >> 1, wc = w & 1;
    const int lr  = l & 15, q = l >> 4;
    const int lrow = l >> 3;            // staging: 8 lanes/row (64 u16 = 128 B rows)
    const int lcol = (l & 7) << 3;      // staging: lane -> 8-elem chunk

    floatx4 acc[TM][TN];
#pragma unroll
    for (int i = 0; i < TM; ++i)
#pragma unroll
        for (int j = 0; j < TN; ++j) acc[i][j] = (floatx4){0.f, 0.f, 0.f, 0.f};

    const u16* Ab = A + (size_t)bm * lda;
    const u16* Bb = B + (size_t)bn * ldb;

    for (int k0 = 0; k0 < K; k0 += 64) {
#pragma unroll
        for (int i = 0; i < BM / 32; ++i) {      // each wave: BM/4 rows in BM/32 passes of 8
            int r0 = w * (BM / 4) + i * 8;
            gload_lds16(Ab + (size_t)(r0 + lrow) * lda + k0 + lcol, &As[r0 * 64]);
        }
#pragma unroll
        for (int i = 0; i < BN / 32; ++i) {
            int r0 = w * (BN / 4) + i * 8;
            gload_lds16(Bb + (size_t)(r0 + lrow) * ldb + k0 + lcol, &Bs[r0 * 64]);
        }
        __syncthreads();

#pragma unroll
        for (int ks = 0; ks < 2; ++ks) {
            short8 fa[TM], fb[TN];
#pragma unroll
            for (int i = 0; i < TM; ++i)
                fa[i] = *(const short8*)&As[(wr * WM + i * 16 + lr) * 64 + ks * 32 + q * 8];
#pragma unroll
            for (int j = 0; j < TN; ++j)
                fb[j] = *(const short8*)&Bs[(wc * WN + j * 16 + lr) * 64 + ks * 32 + q * 8];
#pragma unroll
            for (int i = 0; i < TM; ++i)
#pragma unroll
                for (int j = 0; j < TN; ++j)
                    acc[i][j] = __builtin_amdgcn_mfma_f32_16x16x32_bf16(fa[i], fb[j], acc[i][j], 0, 0, 0);
        }
        __syncthreads();
    }

    // epilogue: C/D layout col = lane&15, row = (lane>>4)*4 + reg  [m89/m91]
#pragma unroll
    for (int j = 0; j < TN; ++j) {
        int n = bn + wc * WN + j * 16 + lr;
        bool nok = (!NGUARD) || (n < N);
        float bv = nok ? bias[n] : 0.f;
#pragma unroll
        for (int i = 0; i < TM; ++i) {
            int m0r = bm + wr * WM + i * 16 + q * 4;
#pragma unroll
            for (int r = 0; r < 4; ++r) {
                float vv = acc[i][j][r] + bv;
                if (RELU) vv = fmaxf(vv, 0.f);
                if (nok) {
                    size_t idx = (size_t)(m0r + r) * ldc + n;
                    if (OUTF32) ((float*)Cv)[idx] = vv;
                    else        ((u16*)Cv)[idx] = f2bf(vv);
                }
            }
        }
    }
}

// ============================ launch ============================
extern "C" void kernel_launch(void* const* d_in, const int* in_sizes, int n_in,
                              void* d_out, int out_size, void* d_ws, size_t ws_size,
                              hipStream_t stream)
{
    const float* x    = (const float*)d_in[0];
    const float* Wih1 = (const float*)d_in[1];
    const float* Whh1 = (const float*)d_in[2];
    const float* bih1 = (const float*)d_in[3];
    const float* bhh1 = (const float*)d_in[4];
    const float* Wih2 = (const float*)d_in[5];
    const float* Whh2 = (const float*)d_in[6];
    const float* bih2 = (const float*)d_in[7];
    const float* bhh2 = (const float*)d_in[8];
    const float* Wih3 = (const float*)d_in[9];
    const float* Whh3 = (const float*)d_in[10];
    const float* bih3 = (const float*)d_in[11];
    const float* bhh3 = (const float*)d_in[12];
    const float* W1 = (const float*)d_in[13];
    const float* b1 = (const float*)d_in[14];
    const float* W2 = (const float*)d_in[15];
    const float* b2 = (const float*)d_in[16];
    const float* W3 = (const float*)d_in[17];
    const float* b3 = (const float*)d_in[18];

    // ws layout (bf16 elems): A1[2048][4928], A2[2048][4096], A3[2048][1024],
    // W1b[4096][4928] (K-padded), W2b[1024][4096], W3b[640][1024] (row-padded). ~91 MB.
    u16* A1  = (u16*)d_ws;
    u16* A2  = A1  + (size_t)2048 * K1P;
    u16* A3  = A2  + (size_t)2048 * 4096;
    u16* W1b = A3  + (size_t)2048 * 1024;
    u16* W2b = W1b + (size_t)4096 * K1P;
    u16* W3b = W2b + (size_t)1024 * 4096;

    // LSTM (blocks 0..1023) + fused weight conversions (blocks 1024..1279)
    lstm3_fused<<<1280, 192, 0, stream>>>(x, Wih1, Whh1, bih1, bhh1,
                                          Wih2, Whh2, bih2, bhh2,
                                          Wih3, Whh3, bih3, bhh3, A1,
                                          W1, W1b, W2, W2b, W3, W3b);

    // L1: [2048,4928] x W1b[4096,4928] -> relu -> A2 [2048,4096]  (bf16 out)
    gemm_bt<128, 128, true, false, false><<<dim3(32, 16), 256, 0, stream>>>(
        A1, K1P, W1b, K1P, b1, A2, 4096, 4096, K1P);

    // L2: [2048,4096] x W2b[1024,4096] -> relu -> A3 [2048,1024]  (bf16 out)
    // 64x64 tile -> 512 blocks = 2/CU (was 256 = 1/CU: latency-hiding starved)
    gemm_bt<64, 64, true, false, false><<<dim3(16, 32), 256, 0, stream>>>(
        A2, 4096, W2b, 4096, b2, A3, 1024, 1024, 4096);

    // L3: [2048,1024] x W3b[640,1024] -> d_out [2048,609]  (fp32 out, store N-guard)
    gemm_bt<64, 64, false, true, true><<<dim3(10, 32), 256, 0, stream>>>(
        A3, 1024, W3b, 1024, b3, d_out, T_SZ, T_SZ, 1024);
}